// Round 1
// baseline (450.605 us; speedup 1.0000x reference)
//
#include <hip/hip_runtime.h>

// LUT piecewise-linear: out = a[idx]*d + b[idx], idx = #{x_i < d}, K=1024 sorted x.
// v3: packed per-bucket records {lower_bound:11b, count:5b} (u16) + fused (a,b)
// float2 pairs.
//   Common case (bucket holds no breakpoint, ~72% of data-weighted evals):
//     chain = rec(ds_read_u16) -> ab(ds_read_b64) -> fma. 2 dependent LDS ops,
//     no xs probe at all (v2 paid a sentinel xs read + 2 separate a/b reads).
//   Non-empty bucket: branchless scan of exactly cnt (<31) xs entries —
//     no sentinel check-read, loop trip = max cnt among active lanes (~1-2).
//   cnt==31 (saturated, never in practice): exact sentinel while-loop fallback.
// Exactness: bucket_of is the same monotone fp32 expression for breakpoints
// (build) and data (eval). i < lo(j) => bucket(x_i) < bucket(v) => x_i < v;
// entries lo..lo+cnt-1 are exactly bucket j's breakpoints; i >= lo+cnt =>
// bucket(x_i) > bucket(v) => x_i >= v. Identical index + fmaf as v2.

#define LUT_K 1024
#define NB    8192   // buckets
#define CNT_SAT 31
#define WS_NEEDED (NB * 2 + 8)  // u16 recs[NB] + float params[2]

__device__ __forceinline__ int bucket_of(float v, float x0, float invw) {
    // trunc(mul(sub)) with forced IEEE ops: identical + monotone in both kernels
    int t = (int)__fmul_rn(__fsub_rn(v, x0), invw);
    t = t < 0 ? 0 : t;
    return t > (NB - 1) ? (NB - 1) : t;
}

__device__ __forceinline__ int lower_bound_bucket(const float* xs, float x0,
                                                  float invw, int target) {
    // first i with bucket_of(xs[i]) >= target (bucket_of monotone in x)
    int lo = 0, hi = LUT_K;
    while (lo < hi) {
        int mid = (lo + hi) >> 1;
        if (bucket_of(xs[mid], x0, invw) < target) lo = mid + 1; else hi = mid;
    }
    return lo;
}

// ws layout: u16 recs[NB] at 0; float {x0, invw} at NB*2. rec = lo | (cnt<<11).
__global__ __launch_bounds__(256) void build_kernel(const float* __restrict__ x, void* ws) {
    __shared__ float xs[LUT_K];
    unsigned short* recs = (unsigned short*)ws;
    float* params = (float*)((char*)ws + NB * 2);
    for (int i = threadIdx.x; i < LUT_K; i += blockDim.x) xs[i] = x[i];
    __syncthreads();
    const float x0 = xs[0];
    const float invw = (float)NB / (xs[LUT_K - 1] - x0);
    if (blockIdx.x == 0 && threadIdx.x == 0) { params[0] = x0; params[1] = invw; }
    int j = blockIdx.x * blockDim.x + threadIdx.x;
    if (j < NB) {
        int lo  = lower_bound_bucket(xs, x0, invw, j);
        int lo2 = lower_bound_bucket(xs, x0, invw, j + 1);
        int cnt = lo2 - lo; if (cnt > CNT_SAT) cnt = CNT_SAT;
        recs[j] = (unsigned short)(lo | (cnt << 11));   // lo<=1024 fits 11b
    }
}

__global__ __launch_bounds__(256) void lut_main(
    const float* __restrict__ data, const float* __restrict__ x,
    const float* __restrict__ a, const float* __restrict__ b,
    const void* __restrict__ ws, float* __restrict__ out, int n4, int use_ws)
{
    __shared__ float xs[LUT_K + 1];
    __shared__ __align__(16) float2 ab[LUT_K + 1];
    __shared__ __align__(16) unsigned short recs[NB];

    for (int i = threadIdx.x; i < LUT_K; i += blockDim.x) xs[i] = x[i];
    for (int i = threadIdx.x; i < LUT_K + 1; i += blockDim.x)
        ab[i] = make_float2(a[i], b[i]);
    if (threadIdx.x == 0) xs[LUT_K] = __builtin_inff();

    float x0, invw;
    if (use_ws) {
        const float* params = (const float*)((const char*)ws + NB * 2);
        x0 = params[0]; invw = params[1];
        const uint2* gr = (const uint2*)ws;          // stage 8B/thread
        uint2* lr = (uint2*)recs;
        for (int i = threadIdx.x; i < NB / 4; i += blockDim.x) lr[i] = gr[i];
        __syncthreads();
    } else {
        // Fallback (tiny/absent workspace): build recs per-block from xs in LDS.
        __syncthreads();                              // xs ready
        x0 = xs[0];
        invw = (float)NB / (xs[LUT_K - 1] - x0);
        for (int j = threadIdx.x; j < NB; j += blockDim.x) {
            int lo  = lower_bound_bucket(xs, x0, invw, j);
            int lo2 = lower_bound_bucket(xs, x0, invw, j + 1);
            int cnt = lo2 - lo; if (cnt > CNT_SAT) cnt = CNT_SAT;
            recs[j] = (unsigned short)(lo | (cnt << 11));
        }
        __syncthreads();
    }

    const float4* __restrict__ in4 = (const float4*)data;
    float4* __restrict__ out4 = (float4*)out;

    auto eval = [&](float v) -> float {
        int j = bucket_of(v, x0, invw);
        unsigned r = recs[j];                 // ds_read_u16
        int idx = (int)(r & 0x7FFu);
        int cnt = (int)(r >> 11);
        if (cnt) {                            // ~28% of lanes; loop trip = max cnt
            int base = idx;
            if (cnt == CNT_SAT) {             // saturated: exact sentinel scan
                while (xs[idx] < v) idx++;
            } else {
                for (int t = 0; t < cnt; ++t)
                    idx += (xs[base + t] < v) ? 1 : 0;   // branchless count
            }
        }
        float2 p = ab[idx];                   // ds_read_b64 (fused a,b)
        return fmaf(p.x, v, p.y);
    };

    // Grid-stride with one-iteration load rotation: next float4 in flight
    // during eval of the current one.
    const int stride = gridDim.x * blockDim.x;
    int i = blockIdx.x * blockDim.x + threadIdx.x;
    bool have = i < n4;
    float4 d = make_float4(0.f, 0.f, 0.f, 0.f);
    if (have) d = in4[i];
    while (have) {
        int ni = i + stride;
        bool have_n = ni < n4;
        float4 dn = make_float4(0.f, 0.f, 0.f, 0.f);
        if (have_n) dn = in4[ni];
        float4 r;
        r.x = eval(d.x);
        r.y = eval(d.y);
        r.z = eval(d.z);
        r.w = eval(d.w);
        out4[i] = r;
        i = ni; d = dn; have = have_n;
    }
}

extern "C" void kernel_launch(void* const* d_in, const int* in_sizes, int n_in,
                              void* d_out, int out_size, void* d_ws, size_t ws_size,
                              hipStream_t stream) {
    const float* data = (const float*)d_in[0];
    const float* x    = (const float*)d_in[1];
    const float* a    = (const float*)d_in[2];
    const float* b    = (const float*)d_in[3];
    float* out = (float*)d_out;

    int n  = in_sizes[0];   // 4096*16384
    int n4 = n >> 2;

    int use_ws = (ws_size >= (size_t)WS_NEEDED) ? 1 : 0;
    if (use_ws)
        build_kernel<<<(NB + 255) / 256, 256, 0, stream>>>(x, d_ws);

    // LDS 28.7 KB/block -> 5 blocks/CU; grid = 5 * 256 CUs, grid-stride loop.
    lut_main<<<1280, 256, 0, stream>>>(data, x, a, b, d_ws, out, n4, use_ws);
}

// Round 2
// 440.894 us; speedup vs baseline: 1.0220x; 1.0220x over previous
//
#include <hip/hip_runtime.h>

// LUT piecewise-linear: out = a[idx]*d + b[idx], idx = #{x_i < d}, K=1024 sorted x.
// v4: branchless fixed-2-probe. Wave-level insight: any per-lane-conditional scan
// is taken by ~every wave (P(no lane) = 0.72^64 ~ 0), so v2/v3's divergent loops
// ran serially on every eval. Instead:
//   idx = lo + (xs[lo] < v) + (xs[lo+1] < v)      // exact while bucket cnt <= 2
// recs gather -> two INDEPENDENT xs probes (latency-overlapped) -> ab gather.
// 4 LDS gathers, chain depth 3, no divergent loop in the common path.
// cnt >= 3 (~0.5% of lanes at NB=8192): continue exact sentinel scan from lo+2.
// Exactness: bucket_of is the same monotone fp32 expression for breakpoints
// (build) and data (eval). i < lo(j) => x_i < v-candidates' bucket => x_i < v is
// counted by probes; entries beyond the bucket have bucket_of > j => x_i > v, so
// their probe compares are false (harmless). Sorted xs gives the prefix property
// the counting needs. Identical index + fmaf as v2/v3.

#define LUT_K 1024
#define NB    8192   // buckets
#define CNT_SAT 31
#define WS_NEEDED (NB * 2 + 8)  // u16 recs[NB] + float params[2]

__device__ __forceinline__ int bucket_of(float v, float x0, float invw) {
    // trunc(mul(sub)) with forced IEEE ops: identical + monotone in both kernels
    int t = (int)__fmul_rn(__fsub_rn(v, x0), invw);
    t = t < 0 ? 0 : t;
    return t > (NB - 1) ? (NB - 1) : t;
}

__device__ __forceinline__ int lower_bound_bucket(const float* xs, float x0,
                                                  float invw, int target) {
    // first i with bucket_of(xs[i]) >= target (bucket_of monotone in x)
    int lo = 0, hi = LUT_K;
    while (lo < hi) {
        int mid = (lo + hi) >> 1;
        if (bucket_of(xs[mid], x0, invw) < target) lo = mid + 1; else hi = mid;
    }
    return lo;
}

// ws layout: u16 recs[NB] at 0; float {x0, invw} at NB*2. rec = lo | (cnt<<11).
__global__ __launch_bounds__(256) void build_kernel(const float* __restrict__ x, void* ws) {
    __shared__ float xs[LUT_K];
    unsigned short* recs = (unsigned short*)ws;
    float* params = (float*)((char*)ws + NB * 2);
    for (int i = threadIdx.x; i < LUT_K; i += blockDim.x) xs[i] = x[i];
    __syncthreads();
    const float x0 = xs[0];
    const float invw = (float)NB / (xs[LUT_K - 1] - x0);
    if (blockIdx.x == 0 && threadIdx.x == 0) { params[0] = x0; params[1] = invw; }
    int j = blockIdx.x * blockDim.x + threadIdx.x;
    if (j < NB) {
        int lo  = lower_bound_bucket(xs, x0, invw, j);
        int lo2 = lower_bound_bucket(xs, x0, invw, j + 1);
        int cnt = lo2 - lo; if (cnt > CNT_SAT) cnt = CNT_SAT;
        recs[j] = (unsigned short)(lo | (cnt << 11));   // lo<=1024 fits 11b
    }
}

__global__ __launch_bounds__(256) void lut_main(
    const float* __restrict__ data, const float* __restrict__ x,
    const float* __restrict__ a, const float* __restrict__ b,
    const void* __restrict__ ws, float* __restrict__ out, int n4, int use_ws)
{
    __shared__ float xs[LUT_K + 2];                     // +2 inf sentinels (probe lo+1, scan)
    __shared__ __align__(16) float2 ab[LUT_K + 1];
    __shared__ __align__(16) unsigned short recs[NB];

    for (int i = threadIdx.x; i < LUT_K; i += blockDim.x) xs[i] = x[i];
    for (int i = threadIdx.x; i < LUT_K + 1; i += blockDim.x)
        ab[i] = make_float2(a[i], b[i]);
    if (threadIdx.x == 0) { xs[LUT_K] = __builtin_inff(); xs[LUT_K + 1] = __builtin_inff(); }

    float x0, invw;
    if (use_ws) {
        const float* params = (const float*)((const char*)ws + NB * 2);
        x0 = params[0]; invw = params[1];
        const uint2* gr = (const uint2*)ws;          // stage 8B/thread
        uint2* lr = (uint2*)recs;
        for (int i = threadIdx.x; i < NB / 4; i += blockDim.x) lr[i] = gr[i];
        __syncthreads();
    } else {
        // Fallback (tiny/absent workspace): build recs per-block from xs in LDS.
        __syncthreads();                              // xs ready
        x0 = xs[0];
        invw = (float)NB / (xs[LUT_K - 1] - x0);
        for (int j = threadIdx.x; j < NB; j += blockDim.x) {
            int lo  = lower_bound_bucket(xs, x0, invw, j);
            int lo2 = lower_bound_bucket(xs, x0, invw, j + 1);
            int cnt = lo2 - lo; if (cnt > CNT_SAT) cnt = CNT_SAT;
            recs[j] = (unsigned short)(lo | (cnt << 11));
        }
        __syncthreads();
    }

    const float4* __restrict__ in4 = (const float4*)data;
    float4* __restrict__ out4 = (float4*)out;

    auto eval = [&](float v) -> float {
        int j = bucket_of(v, x0, invw);
        unsigned r = recs[j];                           // ds_read_u16
        int lo  = (int)(r & 0x7FFu);
        int cnt = (int)(r >> 11);
        // Two independent probes (latency-overlapped); exact while cnt <= 2.
        int idx = lo + (int)(xs[lo] < v) + (int)(xs[lo + 1] < v);
        if (cnt > 2) {                                  // ~0.5% of lanes
            while (xs[idx] < v) idx++;                  // exact; inf sentinel bounds
        }
        float2 p = ab[idx];                             // ds_read_b64 (fused a,b)
        return fmaf(p.x, v, p.y);
    };

    // Grid-stride with one-iteration load rotation: next float4 in flight
    // during eval of the current one.
    const int stride = gridDim.x * blockDim.x;
    int i = blockIdx.x * blockDim.x + threadIdx.x;
    bool have = i < n4;
    float4 d = make_float4(0.f, 0.f, 0.f, 0.f);
    if (have) d = in4[i];
    while (have) {
        int ni = i + stride;
        bool have_n = ni < n4;
        float4 dn = make_float4(0.f, 0.f, 0.f, 0.f);
        if (have_n) dn = in4[ni];
        float4 r;
        r.x = eval(d.x);
        r.y = eval(d.y);
        r.z = eval(d.z);
        r.w = eval(d.w);
        out4[i] = r;
        i = ni; d = dn; have = have_n;
    }
}

extern "C" void kernel_launch(void* const* d_in, const int* in_sizes, int n_in,
                              void* d_out, int out_size, void* d_ws, size_t ws_size,
                              hipStream_t stream) {
    const float* data = (const float*)d_in[0];
    const float* x    = (const float*)d_in[1];
    const float* a    = (const float*)d_in[2];
    const float* b    = (const float*)d_in[3];
    float* out = (float*)d_out;

    int n  = in_sizes[0];   // 4096*16384
    int n4 = n >> 2;

    int use_ws = (ws_size >= (size_t)WS_NEEDED) ? 1 : 0;
    if (use_ws)
        build_kernel<<<(NB + 255) / 256, 256, 0, stream>>>(x, d_ws);

    // LDS 28.8 KB/block -> 5 blocks/CU; grid = 5 * 256 CUs, grid-stride loop.
    lut_main<<<1280, 256, 0, stream>>>(data, x, a, b, d_ws, out, n4, use_ws);
}